// Round 8
// baseline (3622.670 us; speedup 1.0000x reference)
//
#include <hip/hip_runtime.h>

// ---------------------------------------------------------------------------
// 2-layer LSTM (B=256,T=512,H=512,DIN=64) + FC, persistent-kernel wavefront.
// R17: instruction-level fixes. R16 (5.9us/step) evidence:
//  - VGPR_Count=56 -> the 16-iter GEMM phases CANNOT pipeline their L2
//    A-loads (need 64 VGPR in flight); each phase is serial load(300cy)->
//    4xMFMA -> ~1.5-2.5us exposed latency. Fix: explicit f16x8 preload
//    arrays + sched_barrier(0) (pins loads above MFMAs; R11 failed because
//    the scheduler sank the loads). L1's h1-preload overlaps the h0 wait.
//  - single vmcnt counts loads AND stores: wave3's MALL sys-copy stores made
//    every later load-use on that wave wait vmcnt(0) (~1us MALL drain) ->
//    ALL MALL ops (sys copy, drain, cnt bumps, slack polls, publish) move to
//    wave 4; sys copy re-reads the block's own ring chunk (L2). Compute
//    waves touch only L2 loads/LDS/MFMA/plain stores.
//  - fast mode: cell stores write the ring DIRECTLY (16-lane-coalesced 32B
//    runs, L2 write-back) -> LDS transpose + one barrier removed.
// Probe, self-test, fallback protocol, cnt/flag values: R16 semantics.
// fp16 MFMA (16x16x32), fp32 accum, c-state in registers.
// ---------------------------------------------------------------------------

typedef _Float16 f16;
typedef _Float16 f16x8 __attribute__((ext_vector_type(8)));
typedef float    f32x4 __attribute__((ext_vector_type(4)));

constexpr int NB   = 256;
constexpr int NT   = 512;
constexpr int NH   = 512;
constexpr int NDIN = 64;

constexpr int L0_KC = 18;   // 64(x) + 512(h0) = 576 = 18*32
constexpr int L1_KC = 32;   // 512(h0) + 512(h1) = 1024
constexpr int L0_IMG_HALVES = 4 * L0_KC * 64 * 8;
constexpr int L1_IMG_HALVES = 4 * L1_KC * 64 * 8;

constexpr int RING = 16;
constexpr int SLOT_F16 = 131072;  // 256KB per slot: [ht][row][16]

constexpr size_t BAR_OFF   = 0;        // cnt[slot][group]: 128 lines * 128B
constexpr size_t AUX_OFF   = 16384;
constexpr size_t BIAS0_OFF = 20480;
constexpr size_t BIAS1_OFF = 28672;
constexpr size_t FLAG_OFF  = 36864;    // 256 * 128B (w0=steps done, w2=token)
constexpr size_t H0R_OFF   = 131072;
constexpr size_t H1R_OFF   = H0R_OFF + (size_t)RING * SLOT_F16 * 2;   // +4MB
constexpr size_t W0I_OFF   = H1R_OFF + (size_t)RING * SLOT_F16 * 2;   // +4MB
constexpr size_t W1I_OFF   = W0I_OFF + 2359296;
constexpr size_t WS_NEED   = W1I_OFF + 4194304;   // ~14.4 MB

constexpr int LDS_STAGE = 131072;
constexpr int LDS_GO    = 139264;
constexpr int LDS_SIZE  = 139520;

constexpr int WDOG = 1 << 20;   // spin watchdog

// ---------------------------------------------------------------------------
__global__ void prep_weights(const float* __restrict__ Wih0, const float* __restrict__ Whh0,
                             const float* __restrict__ Wih1, const float* __restrict__ Whh1,
                             char* __restrict__ ws) {
    int idx = blockIdx.x * 256 + threadIdx.x;
    const int L0_CH = 32 * 4 * L0_KC * 64;
    const int L1_CH = 32 * 4 * L1_KC * 64;
    if (idx < L0_CH) {
        int lam = idx & 63;
        int kc  = (idx >> 6) % L0_KC;
        int nf  = ((idx >> 6) / L0_KC) & 3;
        int ht  = idx / (64 * L0_KC * 4);
        int g   = nf * NH + ht * 16 + (lam & 15);
        int kb  = kc * 32 + (lam >> 4) * 8;
        f16x8 v;
#pragma unroll
        for (int j = 0; j < 8; ++j) {
            int k = kb + j;
            float val = (k < NDIN) ? Wih0[(size_t)g * NDIN + k]
                                   : Whh0[(size_t)g * NH + (k - NDIN)];
            v[j] = (f16)val;
        }
        f16* dst = (f16*)(ws + W0I_OFF) + (size_t)ht * L0_IMG_HALVES
                 + ((size_t)(nf * L0_KC + kc) * 64 + lam) * 8;
        *(f16x8*)dst = v;
    } else if (idx < L0_CH + L1_CH) {
        int i2  = idx - L0_CH;
        int lam = i2 & 63;
        int kc  = (i2 >> 6) % L1_KC;
        int nf  = ((i2 >> 6) / L1_KC) & 3;
        int ht  = i2 / (64 * L1_KC * 4);
        int g   = nf * NH + ht * 16 + (lam & 15);
        int kb  = kc * 32 + (lam >> 4) * 8;
        f16x8 v;
#pragma unroll
        for (int j = 0; j < 8; ++j) {
            int k = kb + j;
            float val = (k < NH) ? Wih1[(size_t)g * NH + k]
                                 : Whh1[(size_t)g * NH + (k - NH)];
            v[j] = (f16)val;
        }
        f16* dst = (f16*)(ws + W1I_OFF) + (size_t)ht * L1_IMG_HALVES
                 + ((size_t)(nf * L1_KC + kc) * 64 + lam) * 8;
        *(f16x8*)dst = v;
    }
}

__global__ void prep_state(const float* __restrict__ bih0, const float* __restrict__ bhh0,
                           const float* __restrict__ bih1, const float* __restrict__ bhh1,
                           char* __restrict__ ws) {
    int idx    = blockIdx.x * 256 + threadIdx.x;
    int stride = gridDim.x * 256;
    if (idx < 2048) {
        ((float*)(ws + BIAS0_OFF))[idx] = bih0[idx] + bhh0[idx];
    } else if (idx < 4096) {
        int i = idx - 2048;
        ((float*)(ws + BIAS1_OFF))[i] = bih1[i] + bhh1[i];
    }
    uint4 z; z.x = z.y = z.z = z.w = 0u;
    for (int i = idx; i < 1280; i += stride)            // BAR + AUX
        ((uint4*)(ws + BAR_OFF))[i] = z;
    for (int i = idx; i < 2048; i += stride)            // FLAG
        ((uint4*)(ws + FLAG_OFF))[i] = z;
    const int RINGU4 = (int)((size_t)2 * RING * SLOT_F16 * 2 / 16);  // 8MB
    for (int i = idx; i < RINGU4; i += stride)
        ((uint4*)(ws + H0R_OFF))[i] = z;
}

// ---------------------------------------------------------------------------
__device__ __forceinline__ float sigf(float x) { return 1.f / (1.f + __expf(-x)); }
__device__ __forceinline__ float tanhx(float x) { float e = __expf(2.f * x); return 1.f - 2.f / (e + 1.f); }

__device__ __forceinline__ void st8_sys(unsigned long long* p, unsigned long long v) {
    __hip_atomic_store(p, v, __ATOMIC_RELAXED, __HIP_MEMORY_SCOPE_SYSTEM);
}

template <int SLP>
__device__ __forceinline__ void spin_cnt(unsigned* p, unsigned tgt) {
    int it = 0;
    while (__hip_atomic_fetch_add(p, 0u, __ATOMIC_RELAXED, __HIP_MEMORY_SCOPE_AGENT) < tgt) {
        __builtin_amdgcn_s_sleep(SLP);
        if (++it > WDOG) break;
    }
}

#define MFMA16(a, b, c) __builtin_amdgcn_mfma_f32_16x16x32_f16((a), (b), (c), 0, 0, 0)

__global__ __launch_bounds__(320, 1) void lstm_persist(char* __restrict__ ws,
                                                       const float* __restrict__ xin,
                                                       const float* __restrict__ fcW,
                                                       const float* __restrict__ fcb,
                                                       float* __restrict__ out) {
    extern __shared__ __align__(16) char smem[];
    f16*      sW     = (f16*)smem;
    f16*      hstage = (f16*)(smem + LDS_STAGE);
    unsigned* go     = (unsigned*)(smem + LDS_GO);    // go[0]=slack, go[1]=own (fallback)

    const int tid  = threadIdx.x;
    const int lam  = tid & 63;
    const int w    = tid >> 6;       // 0..3 compute (= m-frag), 4 sync/MALL
    const int col  = lam & 15;
    const int quad = lam >> 4;

    const int bid   = blockIdx.x;
    const int gid   = bid & 7;
    const int layer = gid >> 2;
    const int b0    = (gid & 3) * 64;
    const int ht    = bid >> 3;
    const int h0c   = ht * 16;
    const int KCx   = layer ? L1_KC : L0_KC;

    auto cntp = [&](int g, int slot) -> unsigned* {
        return (unsigned*)(ws + BAR_OFF + (size_t)(slot * 8 + g) * 128);
    };
    unsigned* flags = (unsigned*)(ws + FLAG_OFF);
    unsigned* hsk   = (unsigned*)(ws + AUX_OFF);
    unsigned* trdy  = (unsigned*)(ws + AUX_OFF + 128);
    unsigned* modep = (unsigned*)(ws + AUX_OFF + 256);
    unsigned* finp  = (unsigned*)(ws + AUX_OFF + 384);
    unsigned* tpat  = (unsigned*)(ws + AUX_OFF + 1024);
    unsigned* gvote = (unsigned*)(ws + AUX_OFF + 2048);

    // ---- startup phase 1: token + handshake + write-through self-test ----
    if (tid == 0) {
        go[0] = 0u; go[1] = 0u;
        __hip_atomic_store(flags + (size_t)bid * 32 + 2, 0x5EED0000u + (unsigned)bid,
                           __ATOMIC_RELAXED, __HIP_MEMORY_SCOPE_AGENT);
        __hip_atomic_fetch_add(hsk, 1u, __ATOMIC_RELEASE, __HIP_MEMORY_SCOPE_AGENT);
        {
            int it = 0;
            while (__hip_atomic_fetch_add(hsk, 0u, __ATOMIC_RELAXED, __HIP_MEMORY_SCOPE_AGENT) < 256u) {
                __builtin_amdgcn_s_sleep(8);
                if (++it > WDOG) break;
            }
        }
        if (bid == 0) {
            for (int i = 0; i < 16; ++i)
                __hip_atomic_store(tpat + i * 16, 0xC0FFEE00u + (unsigned)i,
                                   __ATOMIC_RELAXED, __HIP_MEMORY_SCOPE_SYSTEM);
            asm volatile("s_waitcnt vmcnt(0)" ::: "memory");
            __hip_atomic_fetch_add(trdy, 1u, __ATOMIC_RELAXED, __HIP_MEMORY_SCOPE_AGENT);
        }
        if (bid == 1) {
            int it = 0;
            while (__hip_atomic_fetch_add(trdy, 0u, __ATOMIC_RELAXED, __HIP_MEMORY_SCOPE_AGENT) < 1u) {
                __builtin_amdgcn_s_sleep(8);
                if (++it > WDOG) break;
            }
            unsigned ok = 1u;
            for (int i = 0; i < 16; ++i)
                if (__hip_atomic_load(tpat + i * 16, __ATOMIC_RELAXED, __HIP_MEMORY_SCOPE_SYSTEM)
                    != 0xC0FFEE00u + (unsigned)i) ok = 0u;
            __hip_atomic_fetch_add(modep, 2u | (ok ? 0u : 1u), __ATOMIC_RELAXED, __HIP_MEMORY_SCOPE_AGENT);
        }
        unsigned mv; int spins = 0;
        while ((mv = __hip_atomic_fetch_add(modep, 0u, __ATOMIC_RELAXED, __HIP_MEMORY_SCOPE_AGENT)) < 2u) {
            __builtin_amdgcn_s_sleep(16);
            if (++spins > (1 << 22)) { mv = 3u; break; }
        }
        ((unsigned*)hstage)[1] = mv & 1u;
    }
    __syncthreads();
    const unsigned needRel = ((unsigned*)hstage)[1];
    __syncthreads();

    // ---- startup phase 2: behavioral co-location probe (wave 0) ----
    if (tid < 64) {
        unsigned seen = (lam < 32) ? 0u : 1u;
        unsigned expv = 0x5EED0000u + (unsigned)(lam * 8 + gid);
        int it = 0, done_at = 1 << 30;
        for (;;) {
            if (!seen && lam < 32) {
                unsigned v = __hip_atomic_load(flags + (size_t)(lam * 8 + gid) * 32 + 2,
                                               __ATOMIC_RELAXED, __HIP_MEMORY_SCOPE_AGENT);
                if (v == expv) seen = 1u;
            }
            ++it;
            if (__all((int)seen)) { done_at = it; break; }
            if (it >= 64) break;
        }
        unsigned ok = (done_at <= 12) ? 1u : 0u;
        if (lam == 0)
            __hip_atomic_fetch_add(gvote + (size_t)gid * 32, 0x10000u | ok,
                                   __ATOMIC_RELAXED, __HIP_MEMORY_SCOPE_AGENT);
    }
    __syncthreads();
    if (tid == 0) {
        unsigned gv = 0u; int sp2 = 0;
        for (;;) {
            gv = __hip_atomic_fetch_add(gvote + (size_t)gid * 32, 0u,
                                        __ATOMIC_RELAXED, __HIP_MEMORY_SCOPE_AGENT);
            if ((gv >> 16) >= 32u) break;
            __builtin_amdgcn_s_sleep(8);
            if (++sp2 > (1 << 20)) { gv = 0u; break; }
        }
        ((unsigned*)hstage)[0] = (((gv >> 16) >= 32u) && ((gv & 0xFFFFu) == 32u)) ? 1u : 0u;
    }
    __syncthreads();
    const unsigned fastgrp = ((unsigned*)hstage)[0];
    unsigned       fastE1  = fastgrp;   // fallback sync-wave demotion flag
    __syncthreads();

    f16* h0ring = (f16*)(ws + H0R_OFF);
    f16* h1ring = (f16*)(ws + H1R_OFF);
    const float* bias = (const float*)(ws + (layer ? BIAS1_OFF : BIAS0_OFF));
    const f16*   wimg = (const f16*)(ws + (layer ? W1I_OFF : W0I_OFF))
                      + (size_t)ht * (layer ? L1_IMG_HALVES : L0_IMG_HALVES);

    {
        const int n16 = KCx * 4 * 64;
        const uint4* src = (const uint4*)wimg;
        uint4* dst = (uint4*)sW;
        for (int i = tid; i < n16; i += 320) dst[i] = src[i];
    }
    __syncthreads();

    const float bi_i = bias[0 * NH + h0c + col];
    const float bi_f = bias[1 * NH + h0c + col];
    const float bi_g = bias[2 * NH + h0c + col];
    const float bi_o = bias[3 * NH + h0c + col];

    float cst[4];
#pragma unroll
    for (int r = 0; r < 4; ++r) cst[r] = 0.f;

    const f16x8* sBf = (const f16x8*)sW;
    const int rA   = b0 + (w & 3) * 16 + col;
    const int rofs = rA * 16 + (quad & 1) * 8;
    const int hq   = (quad >> 1) * 4096;

    unsigned useRmw = 0u;   // per-wave detect demotion
    unsigned vflag  = 0u;   // per-lane cached flag value

    if (w == 4 && lam == 0) {
        if (layer == 1) spin_cnt<4>(cntp(gid - 4, 0), 32u);   // L0 done step 0
        __hip_atomic_store(&go[0], 1u, __ATOMIC_RELAXED, __HIP_MEMORY_SCOPE_WORKGROUP);
    }

    for (int s = 0; s < NT; ++s) {
        const unsigned us = (unsigned)s;

        f32x4 ai = {0.f,0.f,0.f,0.f}, af = {0.f,0.f,0.f,0.f};
        f32x4 ag = {0.f,0.f,0.f,0.f}, ao = {0.f,0.f,0.f,0.f};

        if (fastgrp) {
            // ================= FAST MODE =================
            if (w == 4) {
                // ---- MALL wave: sys copy, slack polls, cnt bumps ----
                if (layer == 0) {
                    if (s > 0) {   // re-read own chunk of slot s-1 (L2) -> sys store (LLC)
                        unsigned long long* cb = (unsigned long long*)
                            ((char*)h0ring + ((size_t)((s - 1) & 15) * SLOT_F16
                                              + (size_t)ht * 4096 + (size_t)b0 * 16) * 2);
                        unsigned long long a0 = cb[lam * 4 + 0], a1 = cb[lam * 4 + 1];
                        unsigned long long a2 = cb[lam * 4 + 2], a3 = cb[lam * 4 + 3];
                        st8_sys(cb + lam * 4 + 0, a0); st8_sys(cb + lam * 4 + 1, a1);
                        st8_sys(cb + lam * 4 + 2, a2); st8_sys(cb + lam * 4 + 3, a3);
                    }
                    // WAR slack for t=s+1 (L1 partner done t-16)
                    if (lam == 0 && s + 1 < NT) {
                        const unsigned t = us + 1u;
                        if (t >= (unsigned)RING)
                            spin_cnt<8>(cntp(gid + 4, (int)(t & 15u)), 32u * (t >> 4));
                    }
                    asm volatile("s_waitcnt vmcnt(0)" ::: "memory");   // sys copy at LLC
                    if (lam == 0 && s > 0) {
                        if (needRel)
                            __hip_atomic_fetch_add(cntp(gid, (s - 1) & 15), 1u, __ATOMIC_RELEASE, __HIP_MEMORY_SCOPE_AGENT);
                        else
                            __hip_atomic_fetch_add(cntp(gid, (s - 1) & 15), 1u, __ATOMIC_RELAXED, __HIP_MEMORY_SCOPE_AGENT);
                    }
                    if (lam == 0 && s + 1 < NT)
                        __hip_atomic_store(&go[0], us + 2u, __ATOMIC_RELAXED, __HIP_MEMORY_SCOPE_WORKGROUP);
                } else {
                    if (lam == 0 && s + 1 < NT) {   // h0[s+1] ready gate
                        const unsigned t = us + 1u;
                        spin_cnt<4>(cntp(gid - 4, (int)(t & 15u)), 32u * ((t >> 4) + 1u));
                        __hip_atomic_store(&go[0], t + 1u, __ATOMIC_RELAXED, __HIP_MEMORY_SCOPE_WORKGROUP);
                    }
                }
            } else {
                // ---- COMPUTE waves: L2 loads / LDS / MFMA / plain stores only ----
                if (layer == 0) {
                    // x preload (no dependency)
                    f16x8 ax[2];
                    {
                        const float* xr = xin + (size_t)rA * (NT * NDIN) + (size_t)s * NDIN + quad * 8;
#pragma unroll
                        for (int j = 0; j < 2; ++j) {
                            float4 f0 = *(const float4*)(xr + j * 32);
                            float4 f1 = *(const float4*)(xr + j * 32 + 4);
                            ax[j][0] = (f16)f0.x; ax[j][1] = (f16)f0.y; ax[j][2] = (f16)f0.z; ax[j][3] = (f16)f0.w;
                            ax[j][4] = (f16)f1.x; ax[j][5] = (f16)f1.y; ax[j][6] = (f16)f1.z; ax[j][7] = (f16)f1.w;
                        }
                    }
                    // WAR gate (LDS spin)
                    {
                        int it = 0;
                        while (__hip_atomic_load(&go[0], __ATOMIC_RELAXED, __HIP_MEMORY_SCOPE_WORKGROUP) <= us) {
                            __builtin_amdgcn_s_sleep(1);
                            if (++it > WDOG) break;
                        }
                    }
                    // self-detect own edge (peers done s-1)
                    if (s > 0) {
                        if (lam >= 32) vflag = 0xFFFFFFFFu;
                        int it = 0;
                        for (;;) {
                            if (lam < 32 && vflag < us) {
                                if (!useRmw)
                                    vflag = __hip_atomic_load(flags + (size_t)(lam * 8 + gid) * 32,
                                                              __ATOMIC_RELAXED, __HIP_MEMORY_SCOPE_AGENT);
                                else
                                    vflag = __hip_atomic_fetch_add(flags + (size_t)(lam * 8 + gid) * 32, 0u,
                                                                   __ATOMIC_RELAXED, __HIP_MEMORY_SCOPE_AGENT);
                            }
                            if (__all((int)(vflag >= us))) break;
                            if (++it > 20000) useRmw = 1u;
                            if (it > WDOG) break;
                            __builtin_amdgcn_s_sleep(1);
                        }
                    }
                    // preload h0[s-1] fragments (16), pinned above MFMAs
                    f16x8 ah[16];
                    {
                        const f16* hpo = h0ring + (size_t)((s + RING - 1) & 15) * SLOT_F16;
#pragma unroll
                        for (int j = 0; j < 16; ++j)
                            ah[j] = *(const f16x8*)(hpo + (size_t)(2 * j) * 4096 + hq + rofs);
                    }
                    __builtin_amdgcn_sched_barrier(0);
#pragma unroll
                    for (int j = 0; j < 2; ++j) {
                        ai = MFMA16(ax[j], sBf[(0 * L0_KC + j) * 64 + lam], ai);
                        af = MFMA16(ax[j], sBf[(1 * L0_KC + j) * 64 + lam], af);
                        ag = MFMA16(ax[j], sBf[(2 * L0_KC + j) * 64 + lam], ag);
                        ao = MFMA16(ax[j], sBf[(3 * L0_KC + j) * 64 + lam], ao);
                    }
#pragma unroll
                    for (int j = 0; j < 16; ++j) {
                        ai = MFMA16(ah[j], sBf[(0 * L0_KC + 2 + j) * 64 + lam], ai);
                        af = MFMA16(ah[j], sBf[(1 * L0_KC + 2 + j) * 64 + lam], af);
                        ag = MFMA16(ah[j], sBf[(2 * L0_KC + 2 + j) * 64 + lam], ag);
                        ao = MFMA16(ah[j], sBf[(3 * L0_KC + 2 + j) * 64 + lam], ao);
                    }
                } else {
                    // self-detect own edge (h1 peers; usually instant — L1 lags L0)
                    if (s > 0) {
                        if (lam >= 32) vflag = 0xFFFFFFFFu;
                        int it = 0;
                        for (;;) {
                            if (lam < 32 && vflag < us) {
                                if (!useRmw)
                                    vflag = __hip_atomic_load(flags + (size_t)(lam * 8 + gid) * 32,
                                                              __ATOMIC_RELAXED, __HIP_MEMORY_SCOPE_AGENT);
                                else
                                    vflag = __hip_atomic_fetch_add(flags + (size_t)(lam * 8 + gid) * 32, 0u,
                                                                   __ATOMIC_RELAXED, __HIP_MEMORY_SCOPE_AGENT);
                            }
                            if (__all((int)(vflag >= us))) break;
                            if (++it > 20000) useRmw = 1u;
                            if (it > WDOG) break;
                            __builtin_amdgcn_s_sleep(1);
                        }
                    }
                    // preload h1[s-1] (16) — overlaps the h0 pacing wait below
                    f16x8 ah1[16];
                    {
                        const f16* hp1 = h1ring + (size_t)((s + RING - 1) & 15) * SLOT_F16;
#pragma unroll
                        for (int j = 0; j < 16; ++j)
                            ah1[j] = *(const f16x8*)(hp1 + (size_t)(2 * j) * 4096 + hq + rofs);
                    }
                    // h0[s] pacing gate (LDS spin; h1 loads in flight meanwhile)
                    {
                        int it = 0;
                        while (__hip_atomic_load(&go[0], __ATOMIC_RELAXED, __HIP_MEMORY_SCOPE_WORKGROUP) <= us) {
                            __builtin_amdgcn_s_sleep(1);
                            if (++it > WDOG) break;
                        }
                    }
                    // preload h0[s] (16)
                    f16x8 ah0[16];
                    {
                        const f16* hp0 = h0ring + (size_t)(s & 15) * SLOT_F16;
#pragma unroll
                        for (int j = 0; j < 16; ++j)
                            ah0[j] = *(const f16x8*)(hp0 + (size_t)(2 * j) * 4096 + hq + rofs);
                    }
                    __builtin_amdgcn_sched_barrier(0);
                    // h1 MFMAs first (their loads complete first)
#pragma unroll
                    for (int j = 0; j < 16; ++j) {
                        ai = MFMA16(ah1[j], sBf[(0 * L1_KC + 16 + j) * 64 + lam], ai);
                        af = MFMA16(ah1[j], sBf[(1 * L1_KC + 16 + j) * 64 + lam], af);
                        ag = MFMA16(ah1[j], sBf[(2 * L1_KC + 16 + j) * 64 + lam], ag);
                        ao = MFMA16(ah1[j], sBf[(3 * L1_KC + 16 + j) * 64 + lam], ao);
                    }
#pragma unroll
                    for (int j = 0; j < 16; ++j) {
                        ai = MFMA16(ah0[j], sBf[(0 * L1_KC + j) * 64 + lam], ai);
                        af = MFMA16(ah0[j], sBf[(1 * L1_KC + j) * 64 + lam], af);
                        ag = MFMA16(ah0[j], sBf[(2 * L1_KC + j) * 64 + lam], ag);
                        ao = MFMA16(ah0[j], sBf[(3 * L1_KC + j) * 64 + lam], ao);
                    }
                }

                // cell update + DIRECT ring store (plain L2 write-back)
                {
                    f16* hwc = (layer ? h1ring : h0ring) + (size_t)(s & 15) * SLOT_F16
                             + (size_t)ht * 4096 + (size_t)b0 * 16;
#pragma unroll
                    for (int r = 0; r < 4; ++r) {
                        float iv = ai[r] + bi_i;
                        float fv = af[r] + bi_f;
                        float gv = ag[r] + bi_g;
                        float ov = ao[r] + bi_o;
                        float cc = sigf(fv) * cst[r] + sigf(iv) * tanhx(gv);
                        cst[r] = cc;
                        float hh = sigf(ov) * tanhx(cc);
                        hwc[((w & 3) * 16 + quad * 4 + r) * 16 + col] = (f16)hh;
                    }
                }
                // staleness bound: one aligned acquire-inv per RING steps
                if (tid == 128 && ((s & 15) == 15))
                    (void)__hip_atomic_load((unsigned*)(ws + BAR_OFF), __ATOMIC_ACQUIRE, __HIP_MEMORY_SCOPE_AGENT);
            }

            __syncthreads();   // drains ring stores (L2); orders step
            if (w == 4 && lam == 0) {   // publish
                __hip_atomic_store(flags + (size_t)bid * 32, us + 1u,
                                   __ATOMIC_RELAXED, __HIP_MEMORY_SCOPE_AGENT);
                if (layer == 1)
                    __hip_atomic_fetch_add(cntp(gid, s & 15), 1u, __ATOMIC_RELAXED, __HIP_MEMORY_SCOPE_AGENT);
            }
        } else {
            // ================= FALLBACK MODE (R16 verbatim) =================
            if (w == 4) {
                if (s > 0) {
                    if (fastE1) {
                        int it = 0;
                        for (;;) {
                            unsigned v = 0xFFFFFFFFu;
                            if (lam < 32)
                                v = __hip_atomic_load(flags + (size_t)(lam * 8 + gid) * 32,
                                                      __ATOMIC_RELAXED, __HIP_MEMORY_SCOPE_AGENT);
                            if (__all((int)(v >= us))) break;
                            if (++it > 20000) { fastE1 = 0u; break; }
                        }
                    }
                    if (!fastE1) {
                        int it = 0;
                        for (;;) {
                            unsigned v = 0xFFFFFFFFu;
                            if (lam < 32)
                                v = __hip_atomic_fetch_add(flags + (size_t)(lam * 8 + gid) * 32, 0u,
                                                           __ATOMIC_RELAXED, __HIP_MEMORY_SCOPE_AGENT);
                            if (__all((int)(v >= us))) break;
                            __builtin_amdgcn_s_sleep(2);
                            if (++it > WDOG) break;
                        }
                    }
                }
                if (lam == 0)
                    __hip_atomic_store(&go[1], us + 1u, __ATOMIC_RELAXED, __HIP_MEMORY_SCOPE_WORKGROUP);
                if (lam == 0 && s + 1 < NT) {
                    const unsigned t = us + 1u;
                    if (layer == 0) {
                        if (t >= (unsigned)RING)
                            spin_cnt<8>(cntp(gid + 4, (int)(t & 15u)), 32u * (t >> 4));
                    } else {
                        spin_cnt<4>(cntp(gid - 4, (int)(t & 15u)), 32u * ((t >> 4) + 1u));
                    }
                    __hip_atomic_store(&go[0], t + 1u, __ATOMIC_RELAXED, __HIP_MEMORY_SCOPE_WORKGROUP);
                }
            } else {
                if (layer == 0) {
                    const float* xr = xin + (size_t)rA * (NT * NDIN) + (size_t)s * NDIN + quad * 8;
#pragma unroll
                    for (int j = 0; j < 2; ++j) {
                        float4 f0 = *(const float4*)(xr + j * 32);
                        float4 f1 = *(const float4*)(xr + j * 32 + 4);
                        f16x8 a;
                        a[0] = (f16)f0.x; a[1] = (f16)f0.y; a[2] = (f16)f0.z; a[3] = (f16)f0.w;
                        a[4] = (f16)f1.x; a[5] = (f16)f1.y; a[6] = (f16)f1.z; a[7] = (f16)f1.w;
                        ai = MFMA16(a, sBf[(0 * L0_KC + j) * 64 + lam], ai);
                        af = MFMA16(a, sBf[(1 * L0_KC + j) * 64 + lam], af);
                        ag = MFMA16(a, sBf[(2 * L0_KC + j) * 64 + lam], ag);
                        ao = MFMA16(a, sBf[(3 * L0_KC + j) * 64 + lam], ao);
                    }
                    int it = 0;
                    while (__hip_atomic_load(&go[0], __ATOMIC_RELAXED, __HIP_MEMORY_SCOPE_WORKGROUP) <= us) {
                        __builtin_amdgcn_s_sleep(1);
                        if (++it > WDOG) break;
                    }
                } else {
                    int it = 0;
                    while (__hip_atomic_load(&go[0], __ATOMIC_RELAXED, __HIP_MEMORY_SCOPE_WORKGROUP) <= us) {
                        __builtin_amdgcn_s_sleep(1);
                        if (++it > WDOG) break;
                    }
                    const f16* hp0 = h0ring + (size_t)(s & 15) * SLOT_F16;
#pragma unroll
                    for (int j = 0; j < 16; ++j) {
                        f16x8 a = *(const f16x8*)(hp0 + (size_t)(2 * j) * 4096 + hq + rofs);
                        ai = MFMA16(a, sBf[(0 * L1_KC + j) * 64 + lam], ai);
                        af = MFMA16(a, sBf[(1 * L1_KC + j) * 64 + lam], af);
                        ag = MFMA16(a, sBf[(2 * L1_KC + j) * 64 + lam], ag);
                        ao = MFMA16(a, sBf[(3 * L1_KC + j) * 64 + lam], ao);
                    }
                }
                {
                    int it = 0;
                    while (__hip_atomic_load(&go[1], __ATOMIC_RELAXED, __HIP_MEMORY_SCOPE_WORKGROUP) <= us) {
                        __builtin_amdgcn_s_sleep(1);
                        if (++it > WDOG) break;
                    }
                }
                {
                    const f16* hpo = (layer ? h1ring : h0ring) + (size_t)((s + RING - 1) & 15) * SLOT_F16;
                    const int  wb  = layer ? 16 : 2;
#pragma unroll
                    for (int j = 0; j < 16; ++j) {
                        f16x8 a = *(const f16x8*)(hpo + (size_t)(2 * j) * 4096 + hq + rofs);
                        ai = MFMA16(a, sBf[(0 * KCx + wb + j) * 64 + lam], ai);
                        af = MFMA16(a, sBf[(1 * KCx + wb + j) * 64 + lam], af);
                        ag = MFMA16(a, sBf[(2 * KCx + wb + j) * 64 + lam], ag);
                        ao = MFMA16(a, sBf[(3 * KCx + wb + j) * 64 + lam], ao);
                    }
                }
#pragma unroll
                for (int r = 0; r < 4; ++r) {
                    float iv = ai[r] + bi_i;
                    float fv = af[r] + bi_f;
                    float gv = ag[r] + bi_g;
                    float ov = ao[r] + bi_o;
                    float cc = sigf(fv) * cst[r] + sigf(iv) * tanhx(gv);
                    cst[r] = cc;
                    float hh = sigf(ov) * tanhx(cc);
                    hstage[((w & 3) * 16 + quad * 4 + r) * 16 + col] = (f16)hh;
                }
            }

            __syncthreads();   // T
            if (tid < 128) {
                f16* dstf = (layer ? h1ring : h0ring)
                          + (size_t)(s & 15) * SLOT_F16 + (size_t)ht * 4096
                          + (size_t)b0 * 16 + (size_t)tid * 8;
                const unsigned long long* sp = (const unsigned long long*)hstage;
                st8_sys((unsigned long long*)dstf, sp[tid * 2]);
                st8_sys((unsigned long long*)dstf + 1, sp[tid * 2 + 1]);
            }
            if (tid == 128 && ((s & 15) == 15))
                (void)__hip_atomic_load((unsigned*)(ws + BAR_OFF), __ATOMIC_ACQUIRE, __HIP_MEMORY_SCOPE_AGENT);
            __syncthreads();   // B4
            if (tid == 192) {
                if (needRel)
                    __hip_atomic_fetch_add(cntp(gid, s & 15), 1u, __ATOMIC_RELEASE, __HIP_MEMORY_SCOPE_AGENT);
                else
                    __hip_atomic_fetch_add(cntp(gid, s & 15), 1u, __ATOMIC_RELAXED, __HIP_MEMORY_SCOPE_AGENT);
                __hip_atomic_fetch_add(flags + (size_t)bid * 32, 1u,
                                       __ATOMIC_RELAXED, __HIP_MEMORY_SCOPE_AGENT);
            }
        }
    }

    // epilogue: fast-L0 sys copy + cnt for step 511 (slot 15), by wave 4
    if (fastgrp && layer == 0 && w == 4) {
        unsigned long long* cb = (unsigned long long*)
            ((char*)h0ring + ((size_t)15 * SLOT_F16 + (size_t)ht * 4096 + (size_t)b0 * 16) * 2);
        unsigned long long a0 = cb[lam * 4 + 0], a1 = cb[lam * 4 + 1];
        unsigned long long a2 = cb[lam * 4 + 2], a3 = cb[lam * 4 + 3];
        st8_sys(cb + lam * 4 + 0, a0); st8_sys(cb + lam * 4 + 1, a1);
        st8_sys(cb + lam * 4 + 2, a2); st8_sys(cb + lam * 4 + 3, a3);
        asm volatile("s_waitcnt vmcnt(0)" ::: "memory");
        if (lam == 0) {
            if (needRel)
                __hip_atomic_fetch_add(cntp(gid, 15), 1u, __ATOMIC_RELEASE, __HIP_MEMORY_SCOPE_AGENT);
            else
                __hip_atomic_fetch_add(cntp(gid, 15), 1u, __ATOMIC_RELAXED, __HIP_MEMORY_SCOPE_AGENT);
        }
    }

    // L1 blocks: final RELEASE (wbl2 flushes agent-dirty h1 to LLC for the FC)
    if (layer == 1 && tid == 0)
        __hip_atomic_fetch_add(finp, 1u, __ATOMIC_RELEASE, __HIP_MEMORY_SCOPE_AGENT);

    if (bid == 0) {
        if (tid == 0) {
            int it = 0;
            while (__hip_atomic_fetch_add(finp, 0u, __ATOMIC_RELAXED, __HIP_MEMORY_SCOPE_AGENT) < 128u) {
                __builtin_amdgcn_s_sleep(8);
                if (++it > (1 << 22)) break;
            }
            (void)__hip_atomic_load((unsigned*)(ws + BAR_OFF), __ATOMIC_ACQUIRE, __HIP_MEMORY_SCOPE_AGENT);
        }
        __syncthreads();
        if (tid < 256) {
            const f16* hrow = h1ring + (size_t)15 * SLOT_F16 + (size_t)tid * 16;  // slot 511&15
            float acc = fcb[0];
#pragma unroll 4
            for (int t2 = 0; t2 < 32; ++t2) {
                f16x8 a = *(const f16x8*)(hrow + t2 * 4096);
                f16x8 b = *(const f16x8*)(hrow + t2 * 4096 + 8);
#pragma unroll
                for (int e = 0; e < 8; ++e)
                    acc += fcW[t2 * 16 + e] * (float)a[e] + fcW[t2 * 16 + 8 + e] * (float)b[e];
            }
            out[tid] = acc;
        }
    }
}

// ---------------------------------------------------------------------------
extern "C" void kernel_launch(void* const* d_in, const int* in_sizes, int n_in,
                              void* d_out, int out_size, void* d_ws, size_t ws_size,
                              hipStream_t stream) {
    const float* x    = (const float*)d_in[0];
    const float* Wih0 = (const float*)d_in[1];
    const float* Whh0 = (const float*)d_in[2];
    const float* bih0 = (const float*)d_in[3];
    const float* bhh0 = (const float*)d_in[4];
    const float* Wih1 = (const float*)d_in[5];
    const float* Whh1 = (const float*)d_in[6];
    const float* bih1 = (const float*)d_in[7];
    const float* bhh1 = (const float*)d_in[8];
    const float* fcW  = (const float*)d_in[9];
    const float* fcb  = (const float*)d_in[10];
    char*  ws  = (char*)d_ws;
    float* out = (float*)d_out;

    if (ws_size < WS_NEED) {
        hipMemsetAsync(d_out, 0, (size_t)out_size * sizeof(float), stream);
        return;
    }

    hipFuncSetAttribute(reinterpret_cast<const void*>(lstm_persist),
                        hipFuncAttributeMaxDynamicSharedMemorySize, LDS_SIZE);

    prep_weights<<<1600, 256, 0, stream>>>(Wih0, Whh0, Wih1, Whh1, ws);
    prep_state<<<1100, 256, 0, stream>>>(bih0, bhh0, bih1, bhh1, ws);
    lstm_persist<<<256, 320, LDS_SIZE, stream>>>(ws, x, fcW, fcb, out);
}

// Round 9
// 2743.237 us; speedup vs baseline: 1.3206x; 1.3206x over previous
//
#include <hip/hip_runtime.h>

// ---------------------------------------------------------------------------
// 2-layer LSTM (B=256,T=512,H=512,DIN=64) + FC, persistent-kernel wavefront.
// R18: R16 base (3027us, passed) + ONE change: 16-deep register preload per
// GEMM phase.
//  R17 post-mortem: bundled 3 changes; regression came from (a) L1 holding
//  TWO 16-frag arrays live (>reg budget -> spill) and (b) scalar 2B ring
//  stores -> L2 write-allocate fetches (+60MB FETCH). The preload itself is
//  sound (VGPR 56->128 proved engagement).
//  Surviving model: L1's h0 slack GEMM is LLC-latency-bound BY DESIGN
//  (write-through h0 -> compulsory L2 miss, ~600cy x 16 serial = ~4us; FETCH
//  171MB == exactly the necessary 128 x 2KB x 512 cross-XCD reads). Own
//  phases are 16 serial L2 hits (~1.3us). Pipelining via preload collapses
//  latency-chains to ~1 load latency + issue.
//  R18 transform (only edit vs R16): each 16-iter GEMM phase becomes
//  {preload 16 f16x8 -> sched_barrier(0) -> 16x4 MFMA}. Phases are separated
//  by the detect, so only ONE 64-VGPR array is ever live (R17's double-live
//  bug structurally impossible). Everything else byte-identical to R16:
//  sync protocol, wave-4 role, LDS-staged full-line ring write, publishes,
//  probe, self-test, fallback, watchdogs.
// fp16 MFMA (16x16x32), fp32 accum, c-state in registers.
// ---------------------------------------------------------------------------

typedef _Float16 f16;
typedef _Float16 f16x8 __attribute__((ext_vector_type(8)));
typedef float    f32x4 __attribute__((ext_vector_type(4)));

constexpr int NB   = 256;
constexpr int NT   = 512;
constexpr int NH   = 512;
constexpr int NDIN = 64;

constexpr int L0_KC = 18;   // 64(x) + 512(h0) = 576 = 18*32
constexpr int L1_KC = 32;   // 512(h0) + 512(h1) = 1024
constexpr int L0_IMG_HALVES = 4 * L0_KC * 64 * 8;
constexpr int L1_IMG_HALVES = 4 * L1_KC * 64 * 8;

constexpr int RING = 16;
constexpr int SLOT_F16 = 131072;  // 256KB per slot: [ht][row][16]

constexpr size_t BAR_OFF   = 0;        // cnt[slot][group]: 128 lines * 128B
constexpr size_t AUX_OFF   = 16384;
constexpr size_t BIAS0_OFF = 20480;
constexpr size_t BIAS1_OFF = 28672;
constexpr size_t FLAG_OFF  = 36864;    // 256 * 128B (w0=steps done, w2=token)
constexpr size_t H0R_OFF   = 131072;
constexpr size_t H1R_OFF   = H0R_OFF + (size_t)RING * SLOT_F16 * 2;   // +4MB
constexpr size_t W0I_OFF   = H1R_OFF + (size_t)RING * SLOT_F16 * 2;   // +4MB
constexpr size_t W1I_OFF   = W0I_OFF + 2359296;
constexpr size_t WS_NEED   = W1I_OFF + 4194304;   // ~14.4 MB

constexpr int LDS_STAGE = 131072;
constexpr int LDS_GO    = 139264;
constexpr int LDS_SIZE  = 139520;

constexpr int WDOG = 1 << 20;   // spin watchdog

// ---------------------------------------------------------------------------
__global__ void prep_weights(const float* __restrict__ Wih0, const float* __restrict__ Whh0,
                             const float* __restrict__ Wih1, const float* __restrict__ Whh1,
                             char* __restrict__ ws) {
    int idx = blockIdx.x * 256 + threadIdx.x;
    const int L0_CH = 32 * 4 * L0_KC * 64;
    const int L1_CH = 32 * 4 * L1_KC * 64;
    if (idx < L0_CH) {
        int lam = idx & 63;
        int kc  = (idx >> 6) % L0_KC;
        int nf  = ((idx >> 6) / L0_KC) & 3;
        int ht  = idx / (64 * L0_KC * 4);
        int g   = nf * NH + ht * 16 + (lam & 15);
        int kb  = kc * 32 + (lam >> 4) * 8;
        f16x8 v;
#pragma unroll
        for (int j = 0; j < 8; ++j) {
            int k = kb + j;
            float val = (k < NDIN) ? Wih0[(size_t)g * NDIN + k]
                                   : Whh0[(size_t)g * NH + (k - NDIN)];
            v[j] = (f16)val;
        }
        f16* dst = (f16*)(ws + W0I_OFF) + (size_t)ht * L0_IMG_HALVES
                 + ((size_t)(nf * L0_KC + kc) * 64 + lam) * 8;
        *(f16x8*)dst = v;
    } else if (idx < L0_CH + L1_CH) {
        int i2  = idx - L0_CH;
        int lam = i2 & 63;
        int kc  = (i2 >> 6) % L1_KC;
        int nf  = ((i2 >> 6) / L1_KC) & 3;
        int ht  = i2 / (64 * L1_KC * 4);
        int g   = nf * NH + ht * 16 + (lam & 15);
        int kb  = kc * 32 + (lam >> 4) * 8;
        f16x8 v;
#pragma unroll
        for (int j = 0; j < 8; ++j) {
            int k = kb + j;
            float val = (k < NH) ? Wih1[(size_t)g * NH + k]
                                 : Whh1[(size_t)g * NH + (k - NH)];
            v[j] = (f16)val;
        }
        f16* dst = (f16*)(ws + W1I_OFF) + (size_t)ht * L1_IMG_HALVES
                 + ((size_t)(nf * L1_KC + kc) * 64 + lam) * 8;
        *(f16x8*)dst = v;
    }
}

__global__ void prep_state(const float* __restrict__ bih0, const float* __restrict__ bhh0,
                           const float* __restrict__ bih1, const float* __restrict__ bhh1,
                           char* __restrict__ ws) {
    int idx    = blockIdx.x * 256 + threadIdx.x;
    int stride = gridDim.x * 256;
    if (idx < 2048) {
        ((float*)(ws + BIAS0_OFF))[idx] = bih0[idx] + bhh0[idx];
    } else if (idx < 4096) {
        int i = idx - 2048;
        ((float*)(ws + BIAS1_OFF))[i] = bih1[i] + bhh1[i];
    }
    uint4 z; z.x = z.y = z.z = z.w = 0u;
    for (int i = idx; i < 1280; i += stride)            // BAR + AUX
        ((uint4*)(ws + BAR_OFF))[i] = z;
    for (int i = idx; i < 2048; i += stride)            // FLAG
        ((uint4*)(ws + FLAG_OFF))[i] = z;
    const int RINGU4 = (int)((size_t)2 * RING * SLOT_F16 * 2 / 16);  // 8MB
    for (int i = idx; i < RINGU4; i += stride)
        ((uint4*)(ws + H0R_OFF))[i] = z;
}

// ---------------------------------------------------------------------------
__device__ __forceinline__ float sigf(float x) { return 1.f / (1.f + __expf(-x)); }
__device__ __forceinline__ float tanhx(float x) { float e = __expf(2.f * x); return 1.f - 2.f / (e + 1.f); }

__device__ __forceinline__ void st8_sys(unsigned long long* p, unsigned long long v) {
    __hip_atomic_store(p, v, __ATOMIC_RELAXED, __HIP_MEMORY_SCOPE_SYSTEM);
}

template <int SLP>
__device__ __forceinline__ void spin_cnt(unsigned* p, unsigned tgt) {
    int it = 0;
    while (__hip_atomic_fetch_add(p, 0u, __ATOMIC_RELAXED, __HIP_MEMORY_SCOPE_AGENT) < tgt) {
        __builtin_amdgcn_s_sleep(SLP);
        if (++it > WDOG) break;
    }
}

#define MFMA16(a, b, c) __builtin_amdgcn_mfma_f32_16x16x32_f16((a), (b), (c), 0, 0, 0)

__global__ __launch_bounds__(320, 1) void lstm_persist(char* __restrict__ ws,
                                                       const float* __restrict__ xin,
                                                       const float* __restrict__ fcW,
                                                       const float* __restrict__ fcb,
                                                       float* __restrict__ out) {
    extern __shared__ __align__(16) char smem[];
    f16*      sW     = (f16*)smem;
    f16*      hstage = (f16*)(smem + LDS_STAGE);
    unsigned* go     = (unsigned*)(smem + LDS_GO);    // go[0]=slack, go[1]=own (fallback)

    const int tid  = threadIdx.x;
    const int lam  = tid & 63;
    const int w    = tid >> 6;       // 0..3 compute (= m-frag), 4 sync
    const int col  = lam & 15;
    const int quad = lam >> 4;

    const int bid   = blockIdx.x;
    const int gid   = bid & 7;
    const int layer = gid >> 2;
    const int b0    = (gid & 3) * 64;
    const int ht    = bid >> 3;
    const int h0c   = ht * 16;
    const int KCx   = layer ? L1_KC : L0_KC;

    auto cntp = [&](int g, int slot) -> unsigned* {
        return (unsigned*)(ws + BAR_OFF + (size_t)(slot * 8 + g) * 128);
    };
    unsigned* flags = (unsigned*)(ws + FLAG_OFF);
    unsigned* hsk   = (unsigned*)(ws + AUX_OFF);
    unsigned* trdy  = (unsigned*)(ws + AUX_OFF + 128);
    unsigned* modep = (unsigned*)(ws + AUX_OFF + 256);
    unsigned* finp  = (unsigned*)(ws + AUX_OFF + 384);
    unsigned* tpat  = (unsigned*)(ws + AUX_OFF + 1024);
    unsigned* gvote = (unsigned*)(ws + AUX_OFF + 2048);

    // ---- startup phase 1: token + handshake + write-through self-test ----
    if (tid == 0) {
        go[0] = 0u; go[1] = 0u;
        __hip_atomic_store(flags + (size_t)bid * 32 + 2, 0x5EED0000u + (unsigned)bid,
                           __ATOMIC_RELAXED, __HIP_MEMORY_SCOPE_AGENT);
        __hip_atomic_fetch_add(hsk, 1u, __ATOMIC_RELEASE, __HIP_MEMORY_SCOPE_AGENT);
        {
            int it = 0;
            while (__hip_atomic_fetch_add(hsk, 0u, __ATOMIC_RELAXED, __HIP_MEMORY_SCOPE_AGENT) < 256u) {
                __builtin_amdgcn_s_sleep(8);
                if (++it > WDOG) break;
            }
        }
        if (bid == 0) {
            for (int i = 0; i < 16; ++i)
                __hip_atomic_store(tpat + i * 16, 0xC0FFEE00u + (unsigned)i,
                                   __ATOMIC_RELAXED, __HIP_MEMORY_SCOPE_SYSTEM);
            asm volatile("s_waitcnt vmcnt(0)" ::: "memory");
            __hip_atomic_fetch_add(trdy, 1u, __ATOMIC_RELAXED, __HIP_MEMORY_SCOPE_AGENT);
        }
        if (bid == 1) {
            int it = 0;
            while (__hip_atomic_fetch_add(trdy, 0u, __ATOMIC_RELAXED, __HIP_MEMORY_SCOPE_AGENT) < 1u) {
                __builtin_amdgcn_s_sleep(8);
                if (++it > WDOG) break;
            }
            unsigned ok = 1u;
            for (int i = 0; i < 16; ++i)
                if (__hip_atomic_load(tpat + i * 16, __ATOMIC_RELAXED, __HIP_MEMORY_SCOPE_SYSTEM)
                    != 0xC0FFEE00u + (unsigned)i) ok = 0u;
            __hip_atomic_fetch_add(modep, 2u | (ok ? 0u : 1u), __ATOMIC_RELAXED, __HIP_MEMORY_SCOPE_AGENT);
        }
        unsigned mv; int spins = 0;
        while ((mv = __hip_atomic_fetch_add(modep, 0u, __ATOMIC_RELAXED, __HIP_MEMORY_SCOPE_AGENT)) < 2u) {
            __builtin_amdgcn_s_sleep(16);
            if (++spins > (1 << 22)) { mv = 3u; break; }
        }
        ((unsigned*)hstage)[1] = mv & 1u;
    }
    __syncthreads();
    const unsigned needRel = ((unsigned*)hstage)[1];
    __syncthreads();

    // ---- startup phase 2: behavioral co-location probe (wave 0) ----
    if (tid < 64) {
        unsigned seen = (lam < 32) ? 0u : 1u;
        unsigned expv = 0x5EED0000u + (unsigned)(lam * 8 + gid);
        int it = 0, done_at = 1 << 30;
        for (;;) {
            if (!seen && lam < 32) {
                unsigned v = __hip_atomic_load(flags + (size_t)(lam * 8 + gid) * 32 + 2,
                                               __ATOMIC_RELAXED, __HIP_MEMORY_SCOPE_AGENT);
                if (v == expv) seen = 1u;
            }
            ++it;
            if (__all((int)seen)) { done_at = it; break; }
            if (it >= 64) break;
        }
        unsigned ok = (done_at <= 12) ? 1u : 0u;
        if (lam == 0)
            __hip_atomic_fetch_add(gvote + (size_t)gid * 32, 0x10000u | ok,
                                   __ATOMIC_RELAXED, __HIP_MEMORY_SCOPE_AGENT);
    }
    __syncthreads();
    if (tid == 0) {
        unsigned gv = 0u; int sp2 = 0;
        for (;;) {
            gv = __hip_atomic_fetch_add(gvote + (size_t)gid * 32, 0u,
                                        __ATOMIC_RELAXED, __HIP_MEMORY_SCOPE_AGENT);
            if ((gv >> 16) >= 32u) break;
            __builtin_amdgcn_s_sleep(8);
            if (++sp2 > (1 << 20)) { gv = 0u; break; }
        }
        ((unsigned*)hstage)[0] = (((gv >> 16) >= 32u) && ((gv & 0xFFFFu) == 32u)) ? 1u : 0u;
    }
    __syncthreads();
    const unsigned fastgrp = ((unsigned*)hstage)[0];
    unsigned       fastE1  = fastgrp;   // fallback sync-wave demotion flag
    __syncthreads();

    f16* h0ring = (f16*)(ws + H0R_OFF);
    f16* h1ring = (f16*)(ws + H1R_OFF);
    const float* bias = (const float*)(ws + (layer ? BIAS1_OFF : BIAS0_OFF));
    const f16*   wimg = (const f16*)(ws + (layer ? W1I_OFF : W0I_OFF))
                      + (size_t)ht * (layer ? L1_IMG_HALVES : L0_IMG_HALVES);

    {
        const int n16 = KCx * 4 * 64;
        const uint4* src = (const uint4*)wimg;
        uint4* dst = (uint4*)sW;
        for (int i = tid; i < n16; i += 320) dst[i] = src[i];
    }
    __syncthreads();

    const float bi_i = bias[0 * NH + h0c + col];
    const float bi_f = bias[1 * NH + h0c + col];
    const float bi_g = bias[2 * NH + h0c + col];
    const float bi_o = bias[3 * NH + h0c + col];

    float cst[4];
#pragma unroll
    for (int r = 0; r < 4; ++r) cst[r] = 0.f;

    const f16x8* sBf = (const f16x8*)sW;
    const int rA   = b0 + (w & 3) * 16 + col;
    const int rofs = rA * 16 + (quad & 1) * 8;
    const int hq   = (quad >> 1) * 4096;

    unsigned useRmw = 0u;   // per-wave detect demotion
    unsigned vflag  = 0u;   // per-lane cached flag value

    if (w == 4 && lam == 0) {
        if (layer == 1) spin_cnt<4>(cntp(gid - 4, 0), 32u);   // L0 done step 0
        __hip_atomic_store(&go[0], 1u, __ATOMIC_RELAXED, __HIP_MEMORY_SCOPE_WORKGROUP);
    }

    for (int s = 0; s < NT; ++s) {
        const unsigned us = (unsigned)s;

        f32x4 ai = {0.f,0.f,0.f,0.f}, af = {0.f,0.f,0.f,0.f};
        f32x4 ag = {0.f,0.f,0.f,0.f}, ao = {0.f,0.f,0.f,0.f};

        if (w == 4) {
            // ===== SYNC WAVE =====
            if (!fastgrp) {
                if (s > 0) {
                    if (fastE1) {
                        int it = 0;
                        for (;;) {
                            unsigned v = 0xFFFFFFFFu;
                            if (lam < 32)
                                v = __hip_atomic_load(flags + (size_t)(lam * 8 + gid) * 32,
                                                      __ATOMIC_RELAXED, __HIP_MEMORY_SCOPE_AGENT);
                            if (__all((int)(v >= us))) break;
                            if (++it > 20000) { fastE1 = 0u; break; }
                        }
                    }
                    if (!fastE1) {
                        int it = 0;
                        for (;;) {
                            unsigned v = 0xFFFFFFFFu;
                            if (lam < 32)
                                v = __hip_atomic_fetch_add(flags + (size_t)(lam * 8 + gid) * 32, 0u,
                                                           __ATOMIC_RELAXED, __HIP_MEMORY_SCOPE_AGENT);
                            if (__all((int)(v >= us))) break;
                            __builtin_amdgcn_s_sleep(2);
                            if (++it > WDOG) break;
                        }
                    }
                }
                if (lam == 0)
                    __hip_atomic_store(&go[1], us + 1u, __ATOMIC_RELAXED, __HIP_MEMORY_SCOPE_WORKGROUP);
            }
            // slack edge for s+1 (both modes; off the critical path)
            if (lam == 0 && s + 1 < NT) {
                const unsigned t = us + 1u;
                if (layer == 0) {
                    if (t >= (unsigned)RING)
                        spin_cnt<8>(cntp(gid + 4, (int)(t & 15u)), 32u * (t >> 4));
                } else {
                    spin_cnt<4>(cntp(gid - 4, (int)(t & 15u)), 32u * ((t >> 4) + 1u));
                }
                __hip_atomic_store(&go[0], t + 1u, __ATOMIC_RELAXED, __HIP_MEMORY_SCOPE_WORKGROUP);
            }
        } else {
            // ===== COMPUTE WAVES =====
            if (layer == 0) {
                const float* xr = xin + (size_t)rA * (NT * NDIN) + (size_t)s * NDIN + quad * 8;
#pragma unroll
                for (int j = 0; j < 2; ++j) {
                    float4 f0 = *(const float4*)(xr + j * 32);
                    float4 f1 = *(const float4*)(xr + j * 32 + 4);
                    f16x8 a;
                    a[0] = (f16)f0.x; a[1] = (f16)f0.y; a[2] = (f16)f0.z; a[3] = (f16)f0.w;
                    a[4] = (f16)f1.x; a[5] = (f16)f1.y; a[6] = (f16)f1.z; a[7] = (f16)f1.w;
                    ai = MFMA16(a, sBf[(0 * L0_KC + j) * 64 + lam], ai);
                    af = MFMA16(a, sBf[(1 * L0_KC + j) * 64 + lam], af);
                    ag = MFMA16(a, sBf[(2 * L0_KC + j) * 64 + lam], ag);
                    ao = MFMA16(a, sBf[(3 * L0_KC + j) * 64 + lam], ao);
                }
                // WAR gate (slack; sleepy, bounded)
                {
                    int it = 0;
                    while (__hip_atomic_load(&go[0], __ATOMIC_RELAXED, __HIP_MEMORY_SCOPE_WORKGROUP) <= us) {
                        __builtin_amdgcn_s_sleep(1);
                        if (++it > WDOG) break;
                    }
                }
            } else {
                // slack-phase gate
                {
                    int it = 0;
                    while (__hip_atomic_load(&go[0], __ATOMIC_RELAXED, __HIP_MEMORY_SCOPE_WORKGROUP) <= us) {
                        __builtin_amdgcn_s_sleep(1);
                        if (++it > WDOG) break;
                    }
                }
                // L1 slack GEMM: h0[s] — LLC-latency-bound loads; preload all 16
                // fragments (64 VGPR), pin above MFMAs, then consume.
                {
                    const f16* hp0 = h0ring + (size_t)(s & 15) * SLOT_F16;
                    f16x8 aa[16];
#pragma unroll
                    for (int j = 0; j < 16; ++j)
                        aa[j] = *(const f16x8*)(hp0 + (size_t)(2 * j) * 4096 + hq + rofs);
                    __builtin_amdgcn_sched_barrier(0);
#pragma unroll
                    for (int j = 0; j < 16; ++j) {
                        ai = MFMA16(aa[j], sBf[(0 * L1_KC + j) * 64 + lam], ai);
                        af = MFMA16(aa[j], sBf[(1 * L1_KC + j) * 64 + lam], af);
                        ag = MFMA16(aa[j], sBf[(2 * L1_KC + j) * 64 + lam], ag);
                        ao = MFMA16(aa[j], sBf[(3 * L1_KC + j) * 64 + lam], ao);
                    }
                }
            }

            // ---- own edge ----
            if (fastgrp) {
                if (s > 0) {
                    if (lam >= 32) vflag = 0xFFFFFFFFu;
                    int it = 0;
                    for (;;) {
                        if (lam < 32 && vflag < us) {
                            if (!useRmw)
                                vflag = __hip_atomic_load(flags + (size_t)(lam * 8 + gid) * 32,
                                                          __ATOMIC_RELAXED, __HIP_MEMORY_SCOPE_AGENT);
                            else
                                vflag = __hip_atomic_fetch_add(flags + (size_t)(lam * 8 + gid) * 32, 0u,
                                                               __ATOMIC_RELAXED, __HIP_MEMORY_SCOPE_AGENT);
                        }
                        if (__all((int)(vflag >= us))) break;
                        if (++it > 20000) useRmw = 1u;   // safety: RMW freshness
                        if (it > WDOG) break;            // watchdog
                        __builtin_amdgcn_s_sleep(1);
                    }
                }
            } else {
                int it = 0;
                while (__hip_atomic_load(&go[1], __ATOMIC_RELAXED, __HIP_MEMORY_SCOPE_WORKGROUP) <= us) {
                    __builtin_amdgcn_s_sleep(1);
                    if (++it > WDOG) break;
                }
            }

            // ---- own-dependent 16 KC: preload-16 then consume ----
            {
                const f16* hpo = (layer ? h1ring : h0ring) + (size_t)((s + RING - 1) & 15) * SLOT_F16;
                const int  wb  = layer ? 16 : 2;
                f16x8 aa[16];
#pragma unroll
                for (int j = 0; j < 16; ++j)
                    aa[j] = *(const f16x8*)(hpo + (size_t)(2 * j) * 4096 + hq + rofs);
                __builtin_amdgcn_sched_barrier(0);
#pragma unroll
                for (int j = 0; j < 16; ++j) {
                    ai = MFMA16(aa[j], sBf[(0 * KCx + wb + j) * 64 + lam], ai);
                    af = MFMA16(aa[j], sBf[(1 * KCx + wb + j) * 64 + lam], af);
                    ag = MFMA16(aa[j], sBf[(2 * KCx + wb + j) * 64 + lam], ag);
                    ao = MFMA16(aa[j], sBf[(3 * KCx + wb + j) * 64 + lam], ao);
                }
            }

            // ---- cell update (wave-local), stage h into LDS ----
#pragma unroll
            for (int r = 0; r < 4; ++r) {
                float iv = ai[r] + bi_i;
                float fv = af[r] + bi_f;
                float gv = ag[r] + bi_g;
                float ov = ao[r] + bi_o;
                float cc = sigf(fv) * cst[r] + sigf(iv) * tanhx(gv);
                cst[r] = cc;
                float hh = sigf(ov) * tanhx(cc);
                hstage[((w & 3) * 16 + quad * 4 + r) * 16 + col] = (f16)hh;
            }
        }

        __syncthreads();   // T: hstage complete; all A-loads consumed

        // ring write: fast = one plain 16B write-back store (dirty L2);
        // fallback = 2x8B system write-through
        if (tid < 128) {
            f16* dstf = (layer ? h1ring : h0ring)
                      + (size_t)(s & 15) * SLOT_F16 + (size_t)ht * 4096
                      + (size_t)b0 * 16 + (size_t)tid * 8;
            if (fastgrp) {
                *(uint4*)dstf = ((const uint4*)hstage)[tid];
            } else {
                const unsigned long long* sp = (const unsigned long long*)hstage;
                st8_sys((unsigned long long*)dstf, sp[tid * 2]);
                st8_sys((unsigned long long*)dstf + 1, sp[tid * 2 + 1]);
            }
        }

        // fast L0: wave 3 captures its hstage rows for the deferred sys copy
        unsigned long long pr0 = 0, pr1 = 0, pr2 = 0, pr3 = 0;
        if (fastgrp && layer == 0 && w == 3) {
            const unsigned long long* sp = (const unsigned long long*)hstage;
            pr0 = sp[lam * 4 + 0]; pr1 = sp[lam * 4 + 1];
            pr2 = sp[lam * 4 + 2]; pr3 = sp[lam * 4 + 3];
        }

        // staleness bound: one aligned acquire-inv per RING steps
        if (tid == 128 && ((s & 15) == 15))
            (void)__hip_atomic_load((unsigned*)(ws + BAR_OFF), __ATOMIC_ACQUIRE, __HIP_MEMORY_SCOPE_AGENT);

        __syncthreads();   // B4: ring stores drained (L2 fast / LLC fallback)

        // fast L0: deferred sys copy of THIS step's chunk (wave 3, after B4;
        // drains under next step's GEMM via the vmcnt below at next B4... the
        // cnt bump waits for it explicitly)
        if (fastgrp && layer == 0 && w == 3) {
            unsigned long long* d = (unsigned long long*)
                ((char*)h0ring + ((size_t)(s & 15) * SLOT_F16 + (size_t)ht * 4096
                                  + (size_t)b0 * 16) * 2) + (size_t)lam * 4;
            st8_sys(d + 0, pr0); st8_sys(d + 1, pr1);
            st8_sys(d + 2, pr2); st8_sys(d + 3, pr3);
            asm volatile("s_waitcnt vmcnt(0)" ::: "memory");
            if (lam == 0) {
                if (needRel)
                    __hip_atomic_fetch_add(cntp(gid, s & 15), 1u, __ATOMIC_RELEASE, __HIP_MEMORY_SCOPE_AGENT);
                else
                    __hip_atomic_fetch_add(cntp(gid, s & 15), 1u, __ATOMIC_RELAXED, __HIP_MEMORY_SCOPE_AGENT);
            }
        }

        if (tid == 192 && !(fastgrp && layer == 0)) {
            // publisher for: fast L1 (flag+cnt) and fallback (both)
            if (fastgrp) {
                __hip_atomic_store(flags + (size_t)bid * 32, us + 1u,
                                   __ATOMIC_RELAXED, __HIP_MEMORY_SCOPE_AGENT);
                __hip_atomic_fetch_add(cntp(gid, s & 15), 1u, __ATOMIC_RELAXED, __HIP_MEMORY_SCOPE_AGENT);
            } else {
                if (needRel)
                    __hip_atomic_fetch_add(cntp(gid, s & 15), 1u, __ATOMIC_RELEASE, __HIP_MEMORY_SCOPE_AGENT);
                else
                    __hip_atomic_fetch_add(cntp(gid, s & 15), 1u, __ATOMIC_RELAXED, __HIP_MEMORY_SCOPE_AGENT);
                __hip_atomic_fetch_add(flags + (size_t)bid * 32, 1u,
                                       __ATOMIC_RELAXED, __HIP_MEMORY_SCOPE_AGENT);
            }
        }
        // fast L0: flag publish (critical edge) by wave-3 lane 32 right after
        // B4 — does NOT wait for the sys-copy drain (same-XCD readers see the
        // plain ring stores drained at B4; cross-XCD readers gate on cnt).
        if (fastgrp && layer == 0 && tid == 192 + 32) {
            __hip_atomic_store(flags + (size_t)bid * 32, us + 1u,
                               __ATOMIC_RELAXED, __HIP_MEMORY_SCOPE_AGENT);
        }
    }

    // L1 blocks: final RELEASE (wbl2 flushes agent-dirty h1 to LLC for the FC)
    if (layer == 1 && tid == 0)
        __hip_atomic_fetch_add(finp, 1u, __ATOMIC_RELEASE, __HIP_MEMORY_SCOPE_AGENT);

    if (bid == 0) {
        if (tid == 0) {
            int it = 0;
            while (__hip_atomic_fetch_add(finp, 0u, __ATOMIC_RELAXED, __HIP_MEMORY_SCOPE_AGENT) < 128u) {
                __builtin_amdgcn_s_sleep(8);
                if (++it > (1 << 22)) break;
            }
            (void)__hip_atomic_load((unsigned*)(ws + BAR_OFF), __ATOMIC_ACQUIRE, __HIP_MEMORY_SCOPE_AGENT);
        }
        __syncthreads();
        if (tid < 256) {
            const f16* hrow = h1ring + (size_t)15 * SLOT_F16 + (size_t)tid * 16;  // slot 511&15
            float acc = fcb[0];
#pragma unroll 4
            for (int t2 = 0; t2 < 32; ++t2) {
                f16x8 a = *(const f16x8*)(hrow + t2 * 4096);
                f16x8 b = *(const f16x8*)(hrow + t2 * 4096 + 8);
#pragma unroll
                for (int e = 0; e < 8; ++e)
                    acc += fcW[t2 * 16 + e] * (float)a[e] + fcW[t2 * 16 + 8 + e] * (float)b[e];
            }
            out[tid] = acc;
        }
    }
}

// ---------------------------------------------------------------------------
extern "C" void kernel_launch(void* const* d_in, const int* in_sizes, int n_in,
                              void* d_out, int out_size, void* d_ws, size_t ws_size,
                              hipStream_t stream) {
    const float* x    = (const float*)d_in[0];
    const float* Wih0 = (const float*)d_in[1];
    const float* Whh0 = (const float*)d_in[2];
    const float* bih0 = (const float*)d_in[3];
    const float* bhh0 = (const float*)d_in[4];
    const float* Wih1 = (const float*)d_in[5];
    const float* Whh1 = (const float*)d_in[6];
    const float* bih1 = (const float*)d_in[7];
    const float* bhh1 = (const float*)d_in[8];
    const float* fcW  = (const float*)d_in[9];
    const float* fcb  = (const float*)d_in[10];
    char*  ws  = (char*)d_ws;
    float* out = (float*)d_out;

    if (ws_size < WS_NEED) {
        hipMemsetAsync(d_out, 0, (size_t)out_size * sizeof(float), stream);
        return;
    }

    hipFuncSetAttribute(reinterpret_cast<const void*>(lstm_persist),
                        hipFuncAttributeMaxDynamicSharedMemorySize, LDS_SIZE);

    prep_weights<<<1600, 256, 0, stream>>>(Wih0, Whh0, Wih1, Whh1, ws);
    prep_state<<<1100, 256, 0, stream>>>(bih0, bhh0, bih1, bhh1, ws);
    lstm_persist<<<256, 320, LDS_SIZE, stream>>>(ws, x, fcW, fcb, out);
}

// Round 10
// 2692.920 us; speedup vs baseline: 1.3453x; 1.0187x over previous
//
#include <hip/hip_runtime.h>

// ---------------------------------------------------------------------------
// 2-layer LSTM (B=256,T=512,H=512,DIN=64) + FC, persistent-kernel wavefront.
// R19: R18 base (2743us, passed) + ONE fix: fast-L0 flag publish off the
// MALL-drain path.
//  R18 post-mortem: VGPR=68 = 16xf16x8 preload fully live (accs in AGPRs) ->
//  GEMM phases pipelined (~0.9us total). Remaining 3.6us/step traced to an
//  ordering bug: the fast-L0 critical flag store was on tid==224 (wave 3),
//  which in program order follows wave 3's deferred sys-copy + vmcnt(0)
//  (~1.1us MALL drain). L0's peers detect THESE flags -> L0 cycle ~5.3us =
//  the measured step time (L0 is the binding side of the wavefront).
//  Fix: fast-L0 flag publish by tid==0 (wave 0) immediately after B4 - wave
//  0's pending stores were already drained at B4, so the store issues with
//  zero wait. Cross-XCD consumers still gate on cnt (still behind the
//  sys-copy drain on wave 3). All other code byte-identical to R18.
// fp16 MFMA (16x16x32), fp32 accum (AGPR), c-state in registers.
// ---------------------------------------------------------------------------

typedef _Float16 f16;
typedef _Float16 f16x8 __attribute__((ext_vector_type(8)));
typedef float    f32x4 __attribute__((ext_vector_type(4)));

constexpr int NB   = 256;
constexpr int NT   = 512;
constexpr int NH   = 512;
constexpr int NDIN = 64;

constexpr int L0_KC = 18;   // 64(x) + 512(h0) = 576 = 18*32
constexpr int L1_KC = 32;   // 512(h0) + 512(h1) = 1024
constexpr int L0_IMG_HALVES = 4 * L0_KC * 64 * 8;
constexpr int L1_IMG_HALVES = 4 * L1_KC * 64 * 8;

constexpr int RING = 16;
constexpr int SLOT_F16 = 131072;  // 256KB per slot: [ht][row][16]

constexpr size_t BAR_OFF   = 0;        // cnt[slot][group]: 128 lines * 128B
constexpr size_t AUX_OFF   = 16384;
constexpr size_t BIAS0_OFF = 20480;
constexpr size_t BIAS1_OFF = 28672;
constexpr size_t FLAG_OFF  = 36864;    // 256 * 128B (w0=steps done, w2=token)
constexpr size_t H0R_OFF   = 131072;
constexpr size_t H1R_OFF   = H0R_OFF + (size_t)RING * SLOT_F16 * 2;   // +4MB
constexpr size_t W0I_OFF   = H1R_OFF + (size_t)RING * SLOT_F16 * 2;   // +4MB
constexpr size_t W1I_OFF   = W0I_OFF + 2359296;
constexpr size_t WS_NEED   = W1I_OFF + 4194304;   // ~14.4 MB

constexpr int LDS_STAGE = 131072;
constexpr int LDS_GO    = 139264;
constexpr int LDS_SIZE  = 139520;

constexpr int WDOG = 1 << 20;   // spin watchdog

// ---------------------------------------------------------------------------
__global__ void prep_weights(const float* __restrict__ Wih0, const float* __restrict__ Whh0,
                             const float* __restrict__ Wih1, const float* __restrict__ Whh1,
                             char* __restrict__ ws) {
    int idx = blockIdx.x * 256 + threadIdx.x;
    const int L0_CH = 32 * 4 * L0_KC * 64;
    const int L1_CH = 32 * 4 * L1_KC * 64;
    if (idx < L0_CH) {
        int lam = idx & 63;
        int kc  = (idx >> 6) % L0_KC;
        int nf  = ((idx >> 6) / L0_KC) & 3;
        int ht  = idx / (64 * L0_KC * 4);
        int g   = nf * NH + ht * 16 + (lam & 15);
        int kb  = kc * 32 + (lam >> 4) * 8;
        f16x8 v;
#pragma unroll
        for (int j = 0; j < 8; ++j) {
            int k = kb + j;
            float val = (k < NDIN) ? Wih0[(size_t)g * NDIN + k]
                                   : Whh0[(size_t)g * NH + (k - NDIN)];
            v[j] = (f16)val;
        }
        f16* dst = (f16*)(ws + W0I_OFF) + (size_t)ht * L0_IMG_HALVES
                 + ((size_t)(nf * L0_KC + kc) * 64 + lam) * 8;
        *(f16x8*)dst = v;
    } else if (idx < L0_CH + L1_CH) {
        int i2  = idx - L0_CH;
        int lam = i2 & 63;
        int kc  = (i2 >> 6) % L1_KC;
        int nf  = ((i2 >> 6) / L1_KC) & 3;
        int ht  = i2 / (64 * L1_KC * 4);
        int g   = nf * NH + ht * 16 + (lam & 15);
        int kb  = kc * 32 + (lam >> 4) * 8;
        f16x8 v;
#pragma unroll
        for (int j = 0; j < 8; ++j) {
            int k = kb + j;
            float val = (k < NH) ? Wih1[(size_t)g * NH + k]
                                 : Whh1[(size_t)g * NH + (k - NH)];
            v[j] = (f16)val;
        }
        f16* dst = (f16*)(ws + W1I_OFF) + (size_t)ht * L1_IMG_HALVES
                 + ((size_t)(nf * L1_KC + kc) * 64 + lam) * 8;
        *(f16x8*)dst = v;
    }
}

__global__ void prep_state(const float* __restrict__ bih0, const float* __restrict__ bhh0,
                           const float* __restrict__ bih1, const float* __restrict__ bhh1,
                           char* __restrict__ ws) {
    int idx    = blockIdx.x * 256 + threadIdx.x;
    int stride = gridDim.x * 256;
    if (idx < 2048) {
        ((float*)(ws + BIAS0_OFF))[idx] = bih0[idx] + bhh0[idx];
    } else if (idx < 4096) {
        int i = idx - 2048;
        ((float*)(ws + BIAS1_OFF))[i] = bih1[i] + bhh1[i];
    }
    uint4 z; z.x = z.y = z.z = z.w = 0u;
    for (int i = idx; i < 1280; i += stride)            // BAR + AUX
        ((uint4*)(ws + BAR_OFF))[i] = z;
    for (int i = idx; i < 2048; i += stride)            // FLAG
        ((uint4*)(ws + FLAG_OFF))[i] = z;
    const int RINGU4 = (int)((size_t)2 * RING * SLOT_F16 * 2 / 16);  // 8MB
    for (int i = idx; i < RINGU4; i += stride)
        ((uint4*)(ws + H0R_OFF))[i] = z;
}

// ---------------------------------------------------------------------------
__device__ __forceinline__ float sigf(float x) { return 1.f / (1.f + __expf(-x)); }
__device__ __forceinline__ float tanhx(float x) { float e = __expf(2.f * x); return 1.f - 2.f / (e + 1.f); }

__device__ __forceinline__ void st8_sys(unsigned long long* p, unsigned long long v) {
    __hip_atomic_store(p, v, __ATOMIC_RELAXED, __HIP_MEMORY_SCOPE_SYSTEM);
}

template <int SLP>
__device__ __forceinline__ void spin_cnt(unsigned* p, unsigned tgt) {
    int it = 0;
    while (__hip_atomic_fetch_add(p, 0u, __ATOMIC_RELAXED, __HIP_MEMORY_SCOPE_AGENT) < tgt) {
        __builtin_amdgcn_s_sleep(SLP);
        if (++it > WDOG) break;
    }
}

#define MFMA16(a, b, c) __builtin_amdgcn_mfma_f32_16x16x32_f16((a), (b), (c), 0, 0, 0)

__global__ __launch_bounds__(320, 1) void lstm_persist(char* __restrict__ ws,
                                                       const float* __restrict__ xin,
                                                       const float* __restrict__ fcW,
                                                       const float* __restrict__ fcb,
                                                       float* __restrict__ out) {
    extern __shared__ __align__(16) char smem[];
    f16*      sW     = (f16*)smem;
    f16*      hstage = (f16*)(smem + LDS_STAGE);
    unsigned* go     = (unsigned*)(smem + LDS_GO);    // go[0]=slack, go[1]=own (fallback)

    const int tid  = threadIdx.x;
    const int lam  = tid & 63;
    const int w    = tid >> 6;       // 0..3 compute (= m-frag), 4 sync
    const int col  = lam & 15;
    const int quad = lam >> 4;

    const int bid   = blockIdx.x;
    const int gid   = bid & 7;
    const int layer = gid >> 2;
    const int b0    = (gid & 3) * 64;
    const int ht    = bid >> 3;
    const int h0c   = ht * 16;
    const int KCx   = layer ? L1_KC : L0_KC;

    auto cntp = [&](int g, int slot) -> unsigned* {
        return (unsigned*)(ws + BAR_OFF + (size_t)(slot * 8 + g) * 128);
    };
    unsigned* flags = (unsigned*)(ws + FLAG_OFF);
    unsigned* hsk   = (unsigned*)(ws + AUX_OFF);
    unsigned* trdy  = (unsigned*)(ws + AUX_OFF + 128);
    unsigned* modep = (unsigned*)(ws + AUX_OFF + 256);
    unsigned* finp  = (unsigned*)(ws + AUX_OFF + 384);
    unsigned* tpat  = (unsigned*)(ws + AUX_OFF + 1024);
    unsigned* gvote = (unsigned*)(ws + AUX_OFF + 2048);

    // ---- startup phase 1: token + handshake + write-through self-test ----
    if (tid == 0) {
        go[0] = 0u; go[1] = 0u;
        __hip_atomic_store(flags + (size_t)bid * 32 + 2, 0x5EED0000u + (unsigned)bid,
                           __ATOMIC_RELAXED, __HIP_MEMORY_SCOPE_AGENT);
        __hip_atomic_fetch_add(hsk, 1u, __ATOMIC_RELEASE, __HIP_MEMORY_SCOPE_AGENT);
        {
            int it = 0;
            while (__hip_atomic_fetch_add(hsk, 0u, __ATOMIC_RELAXED, __HIP_MEMORY_SCOPE_AGENT) < 256u) {
                __builtin_amdgcn_s_sleep(8);
                if (++it > WDOG) break;
            }
        }
        if (bid == 0) {
            for (int i = 0; i < 16; ++i)
                __hip_atomic_store(tpat + i * 16, 0xC0FFEE00u + (unsigned)i,
                                   __ATOMIC_RELAXED, __HIP_MEMORY_SCOPE_SYSTEM);
            asm volatile("s_waitcnt vmcnt(0)" ::: "memory");
            __hip_atomic_fetch_add(trdy, 1u, __ATOMIC_RELAXED, __HIP_MEMORY_SCOPE_AGENT);
        }
        if (bid == 1) {
            int it = 0;
            while (__hip_atomic_fetch_add(trdy, 0u, __ATOMIC_RELAXED, __HIP_MEMORY_SCOPE_AGENT) < 1u) {
                __builtin_amdgcn_s_sleep(8);
                if (++it > WDOG) break;
            }
            unsigned ok = 1u;
            for (int i = 0; i < 16; ++i)
                if (__hip_atomic_load(tpat + i * 16, __ATOMIC_RELAXED, __HIP_MEMORY_SCOPE_SYSTEM)
                    != 0xC0FFEE00u + (unsigned)i) ok = 0u;
            __hip_atomic_fetch_add(modep, 2u | (ok ? 0u : 1u), __ATOMIC_RELAXED, __HIP_MEMORY_SCOPE_AGENT);
        }
        unsigned mv; int spins = 0;
        while ((mv = __hip_atomic_fetch_add(modep, 0u, __ATOMIC_RELAXED, __HIP_MEMORY_SCOPE_AGENT)) < 2u) {
            __builtin_amdgcn_s_sleep(16);
            if (++spins > (1 << 22)) { mv = 3u; break; }
        }
        ((unsigned*)hstage)[1] = mv & 1u;
    }
    __syncthreads();
    const unsigned needRel = ((unsigned*)hstage)[1];
    __syncthreads();

    // ---- startup phase 2: behavioral co-location probe (wave 0) ----
    if (tid < 64) {
        unsigned seen = (lam < 32) ? 0u : 1u;
        unsigned expv = 0x5EED0000u + (unsigned)(lam * 8 + gid);
        int it = 0, done_at = 1 << 30;
        for (;;) {
            if (!seen && lam < 32) {
                unsigned v = __hip_atomic_load(flags + (size_t)(lam * 8 + gid) * 32 + 2,
                                               __ATOMIC_RELAXED, __HIP_MEMORY_SCOPE_AGENT);
                if (v == expv) seen = 1u;
            }
            ++it;
            if (__all((int)seen)) { done_at = it; break; }
            if (it >= 64) break;
        }
        unsigned ok = (done_at <= 12) ? 1u : 0u;
        if (lam == 0)
            __hip_atomic_fetch_add(gvote + (size_t)gid * 32, 0x10000u | ok,
                                   __ATOMIC_RELAXED, __HIP_MEMORY_SCOPE_AGENT);
    }
    __syncthreads();
    if (tid == 0) {
        unsigned gv = 0u; int sp2 = 0;
        for (;;) {
            gv = __hip_atomic_fetch_add(gvote + (size_t)gid * 32, 0u,
                                        __ATOMIC_RELAXED, __HIP_MEMORY_SCOPE_AGENT);
            if ((gv >> 16) >= 32u) break;
            __builtin_amdgcn_s_sleep(8);
            if (++sp2 > (1 << 20)) { gv = 0u; break; }
        }
        ((unsigned*)hstage)[0] = (((gv >> 16) >= 32u) && ((gv & 0xFFFFu) == 32u)) ? 1u : 0u;
    }
    __syncthreads();
    const unsigned fastgrp = ((unsigned*)hstage)[0];
    unsigned       fastE1  = fastgrp;   // fallback sync-wave demotion flag
    __syncthreads();

    f16* h0ring = (f16*)(ws + H0R_OFF);
    f16* h1ring = (f16*)(ws + H1R_OFF);
    const float* bias = (const float*)(ws + (layer ? BIAS1_OFF : BIAS0_OFF));
    const f16*   wimg = (const f16*)(ws + (layer ? W1I_OFF : W0I_OFF))
                      + (size_t)ht * (layer ? L1_IMG_HALVES : L0_IMG_HALVES);

    {
        const int n16 = KCx * 4 * 64;
        const uint4* src = (const uint4*)wimg;
        uint4* dst = (uint4*)sW;
        for (int i = tid; i < n16; i += 320) dst[i] = src[i];
    }
    __syncthreads();

    const float bi_i = bias[0 * NH + h0c + col];
    const float bi_f = bias[1 * NH + h0c + col];
    const float bi_g = bias[2 * NH + h0c + col];
    const float bi_o = bias[3 * NH + h0c + col];

    float cst[4];
#pragma unroll
    for (int r = 0; r < 4; ++r) cst[r] = 0.f;

    const f16x8* sBf = (const f16x8*)sW;
    const int rA   = b0 + (w & 3) * 16 + col;
    const int rofs = rA * 16 + (quad & 1) * 8;
    const int hq   = (quad >> 1) * 4096;

    unsigned useRmw = 0u;   // per-wave detect demotion
    unsigned vflag  = 0u;   // per-lane cached flag value

    if (w == 4 && lam == 0) {
        if (layer == 1) spin_cnt<4>(cntp(gid - 4, 0), 32u);   // L0 done step 0
        __hip_atomic_store(&go[0], 1u, __ATOMIC_RELAXED, __HIP_MEMORY_SCOPE_WORKGROUP);
    }

    for (int s = 0; s < NT; ++s) {
        const unsigned us = (unsigned)s;

        f32x4 ai = {0.f,0.f,0.f,0.f}, af = {0.f,0.f,0.f,0.f};
        f32x4 ag = {0.f,0.f,0.f,0.f}, ao = {0.f,0.f,0.f,0.f};

        if (w == 4) {
            // ===== SYNC WAVE =====
            if (!fastgrp) {
                if (s > 0) {
                    if (fastE1) {
                        int it = 0;
                        for (;;) {
                            unsigned v = 0xFFFFFFFFu;
                            if (lam < 32)
                                v = __hip_atomic_load(flags + (size_t)(lam * 8 + gid) * 32,
                                                      __ATOMIC_RELAXED, __HIP_MEMORY_SCOPE_AGENT);
                            if (__all((int)(v >= us))) break;
                            if (++it > 20000) { fastE1 = 0u; break; }
                        }
                    }
                    if (!fastE1) {
                        int it = 0;
                        for (;;) {
                            unsigned v = 0xFFFFFFFFu;
                            if (lam < 32)
                                v = __hip_atomic_fetch_add(flags + (size_t)(lam * 8 + gid) * 32, 0u,
                                                           __ATOMIC_RELAXED, __HIP_MEMORY_SCOPE_AGENT);
                            if (__all((int)(v >= us))) break;
                            __builtin_amdgcn_s_sleep(2);
                            if (++it > WDOG) break;
                        }
                    }
                }
                if (lam == 0)
                    __hip_atomic_store(&go[1], us + 1u, __ATOMIC_RELAXED, __HIP_MEMORY_SCOPE_WORKGROUP);
            }
            // slack edge for s+1 (both modes; off the critical path)
            if (lam == 0 && s + 1 < NT) {
                const unsigned t = us + 1u;
                if (layer == 0) {
                    if (t >= (unsigned)RING)
                        spin_cnt<8>(cntp(gid + 4, (int)(t & 15u)), 32u * (t >> 4));
                } else {
                    spin_cnt<4>(cntp(gid - 4, (int)(t & 15u)), 32u * ((t >> 4) + 1u));
                }
                __hip_atomic_store(&go[0], t + 1u, __ATOMIC_RELAXED, __HIP_MEMORY_SCOPE_WORKGROUP);
            }
        } else {
            // ===== COMPUTE WAVES =====
            if (layer == 0) {
                const float* xr = xin + (size_t)rA * (NT * NDIN) + (size_t)s * NDIN + quad * 8;
#pragma unroll
                for (int j = 0; j < 2; ++j) {
                    float4 f0 = *(const float4*)(xr + j * 32);
                    float4 f1 = *(const float4*)(xr + j * 32 + 4);
                    f16x8 a;
                    a[0] = (f16)f0.x; a[1] = (f16)f0.y; a[2] = (f16)f0.z; a[3] = (f16)f0.w;
                    a[4] = (f16)f1.x; a[5] = (f16)f1.y; a[6] = (f16)f1.z; a[7] = (f16)f1.w;
                    ai = MFMA16(a, sBf[(0 * L0_KC + j) * 64 + lam], ai);
                    af = MFMA16(a, sBf[(1 * L0_KC + j) * 64 + lam], af);
                    ag = MFMA16(a, sBf[(2 * L0_KC + j) * 64 + lam], ag);
                    ao = MFMA16(a, sBf[(3 * L0_KC + j) * 64 + lam], ao);
                }
                // WAR gate (slack; sleepy, bounded)
                {
                    int it = 0;
                    while (__hip_atomic_load(&go[0], __ATOMIC_RELAXED, __HIP_MEMORY_SCOPE_WORKGROUP) <= us) {
                        __builtin_amdgcn_s_sleep(1);
                        if (++it > WDOG) break;
                    }
                }
            } else {
                // slack-phase gate
                {
                    int it = 0;
                    while (__hip_atomic_load(&go[0], __ATOMIC_RELAXED, __HIP_MEMORY_SCOPE_WORKGROUP) <= us) {
                        __builtin_amdgcn_s_sleep(1);
                        if (++it > WDOG) break;
                    }
                }
                // L1 slack GEMM: h0[s] — preload 16 frags, pin, consume
                {
                    const f16* hp0 = h0ring + (size_t)(s & 15) * SLOT_F16;
                    f16x8 aa[16];
#pragma unroll
                    for (int j = 0; j < 16; ++j)
                        aa[j] = *(const f16x8*)(hp0 + (size_t)(2 * j) * 4096 + hq + rofs);
                    __builtin_amdgcn_sched_barrier(0);
#pragma unroll
                    for (int j = 0; j < 16; ++j) {
                        ai = MFMA16(aa[j], sBf[(0 * L1_KC + j) * 64 + lam], ai);
                        af = MFMA16(aa[j], sBf[(1 * L1_KC + j) * 64 + lam], af);
                        ag = MFMA16(aa[j], sBf[(2 * L1_KC + j) * 64 + lam], ag);
                        ao = MFMA16(aa[j], sBf[(3 * L1_KC + j) * 64 + lam], ao);
                    }
                }
            }

            // ---- own edge ----
            if (fastgrp) {
                if (s > 0) {
                    if (lam >= 32) vflag = 0xFFFFFFFFu;
                    int it = 0;
                    for (;;) {
                        if (lam < 32 && vflag < us) {
                            if (!useRmw)
                                vflag = __hip_atomic_load(flags + (size_t)(lam * 8 + gid) * 32,
                                                          __ATOMIC_RELAXED, __HIP_MEMORY_SCOPE_AGENT);
                            else
                                vflag = __hip_atomic_fetch_add(flags + (size_t)(lam * 8 + gid) * 32, 0u,
                                                               __ATOMIC_RELAXED, __HIP_MEMORY_SCOPE_AGENT);
                        }
                        if (__all((int)(vflag >= us))) break;
                        if (++it > 20000) useRmw = 1u;   // safety: RMW freshness
                        if (it > WDOG) break;            // watchdog
                        __builtin_amdgcn_s_sleep(1);
                    }
                }
            } else {
                int it = 0;
                while (__hip_atomic_load(&go[1], __ATOMIC_RELAXED, __HIP_MEMORY_SCOPE_WORKGROUP) <= us) {
                    __builtin_amdgcn_s_sleep(1);
                    if (++it > WDOG) break;
                }
            }

            // ---- own-dependent 16 KC: preload-16 then consume ----
            {
                const f16* hpo = (layer ? h1ring : h0ring) + (size_t)((s + RING - 1) & 15) * SLOT_F16;
                const int  wb  = layer ? 16 : 2;
                f16x8 aa[16];
#pragma unroll
                for (int j = 0; j < 16; ++j)
                    aa[j] = *(const f16x8*)(hpo + (size_t)(2 * j) * 4096 + hq + rofs);
                __builtin_amdgcn_sched_barrier(0);
#pragma unroll
                for (int j = 0; j < 16; ++j) {
                    ai = MFMA16(aa[j], sBf[(0 * KCx + wb + j) * 64 + lam], ai);
                    af = MFMA16(aa[j], sBf[(1 * KCx + wb + j) * 64 + lam], af);
                    ag = MFMA16(aa[j], sBf[(2 * KCx + wb + j) * 64 + lam], ag);
                    ao = MFMA16(aa[j], sBf[(3 * KCx + wb + j) * 64 + lam], ao);
                }
            }

            // ---- cell update (wave-local), stage h into LDS ----
#pragma unroll
            for (int r = 0; r < 4; ++r) {
                float iv = ai[r] + bi_i;
                float fv = af[r] + bi_f;
                float gv = ag[r] + bi_g;
                float ov = ao[r] + bi_o;
                float cc = sigf(fv) * cst[r] + sigf(iv) * tanhx(gv);
                cst[r] = cc;
                float hh = sigf(ov) * tanhx(cc);
                hstage[((w & 3) * 16 + quad * 4 + r) * 16 + col] = (f16)hh;
            }
        }

        __syncthreads();   // T: hstage complete; all A-loads consumed

        // ring write: fast = one plain 16B write-back store (dirty L2);
        // fallback = 2x8B system write-through
        if (tid < 128) {
            f16* dstf = (layer ? h1ring : h0ring)
                      + (size_t)(s & 15) * SLOT_F16 + (size_t)ht * 4096
                      + (size_t)b0 * 16 + (size_t)tid * 8;
            if (fastgrp) {
                *(uint4*)dstf = ((const uint4*)hstage)[tid];
            } else {
                const unsigned long long* sp = (const unsigned long long*)hstage;
                st8_sys((unsigned long long*)dstf, sp[tid * 2]);
                st8_sys((unsigned long long*)dstf + 1, sp[tid * 2 + 1]);
            }
        }

        // fast L0: wave 3 captures its hstage rows for the deferred sys copy
        unsigned long long pr0 = 0, pr1 = 0, pr2 = 0, pr3 = 0;
        if (fastgrp && layer == 0 && w == 3) {
            const unsigned long long* sp = (const unsigned long long*)hstage;
            pr0 = sp[lam * 4 + 0]; pr1 = sp[lam * 4 + 1];
            pr2 = sp[lam * 4 + 2]; pr3 = sp[lam * 4 + 3];
        }

        // staleness bound: one aligned acquire-inv per RING steps
        if (tid == 128 && ((s & 15) == 15))
            (void)__hip_atomic_load((unsigned*)(ws + BAR_OFF), __ATOMIC_ACQUIRE, __HIP_MEMORY_SCOPE_AGENT);

        __syncthreads();   // B4: ring stores drained (L2 fast / LLC fallback)

        // fast L0: CRITICAL flag publish by wave 0 (tid 0) — wave 0 has no
        // pending VM ops after B4, so this issues with zero wait. L0 peers
        // (same XCD) read the flag + the L2-drained ring data. [R19 fix:
        // was on wave 3 AFTER the sys-copy vmcnt(0) -> ~1.1us on the
        // critical edge every step]
        if (fastgrp && layer == 0 && tid == 0) {
            __hip_atomic_store(flags + (size_t)bid * 32, us + 1u,
                               __ATOMIC_RELAXED, __HIP_MEMORY_SCOPE_AGENT);
        }

        // fast L0: deferred sys copy of THIS step's chunk (wave 3); the cnt
        // bump (cross-XCD consumers) waits for the drain explicitly.
        if (fastgrp && layer == 0 && w == 3) {
            unsigned long long* d = (unsigned long long*)
                ((char*)h0ring + ((size_t)(s & 15) * SLOT_F16 + (size_t)ht * 4096
                                  + (size_t)b0 * 16) * 2) + (size_t)lam * 4;
            st8_sys(d + 0, pr0); st8_sys(d + 1, pr1);
            st8_sys(d + 2, pr2); st8_sys(d + 3, pr3);
            asm volatile("s_waitcnt vmcnt(0)" ::: "memory");
            if (lam == 0) {
                if (needRel)
                    __hip_atomic_fetch_add(cntp(gid, s & 15), 1u, __ATOMIC_RELEASE, __HIP_MEMORY_SCOPE_AGENT);
                else
                    __hip_atomic_fetch_add(cntp(gid, s & 15), 1u, __ATOMIC_RELAXED, __HIP_MEMORY_SCOPE_AGENT);
            }
        }

        if (tid == 192 && !(fastgrp && layer == 0)) {
            // publisher for: fast L1 (flag+cnt) and fallback (both)
            if (fastgrp) {
                __hip_atomic_store(flags + (size_t)bid * 32, us + 1u,
                                   __ATOMIC_RELAXED, __HIP_MEMORY_SCOPE_AGENT);
                __hip_atomic_fetch_add(cntp(gid, s & 15), 1u, __ATOMIC_RELAXED, __HIP_MEMORY_SCOPE_AGENT);
            } else {
                if (needRel)
                    __hip_atomic_fetch_add(cntp(gid, s & 15), 1u, __ATOMIC_RELEASE, __HIP_MEMORY_SCOPE_AGENT);
                else
                    __hip_atomic_fetch_add(cntp(gid, s & 15), 1u, __ATOMIC_RELAXED, __HIP_MEMORY_SCOPE_AGENT);
                __hip_atomic_fetch_add(flags + (size_t)bid * 32, 1u,
                                       __ATOMIC_RELAXED, __HIP_MEMORY_SCOPE_AGENT);
            }
        }
    }

    // L1 blocks: final RELEASE (wbl2 flushes agent-dirty h1 to LLC for the FC)
    if (layer == 1 && tid == 0)
        __hip_atomic_fetch_add(finp, 1u, __ATOMIC_RELEASE, __HIP_MEMORY_SCOPE_AGENT);

    if (bid == 0) {
        if (tid == 0) {
            int it = 0;
            while (__hip_atomic_fetch_add(finp, 0u, __ATOMIC_RELAXED, __HIP_MEMORY_SCOPE_AGENT) < 128u) {
                __builtin_amdgcn_s_sleep(8);
                if (++it > (1 << 22)) break;
            }
            (void)__hip_atomic_load((unsigned*)(ws + BAR_OFF), __ATOMIC_ACQUIRE, __HIP_MEMORY_SCOPE_AGENT);
        }
        __syncthreads();
        if (tid < 256) {
            const f16* hrow = h1ring + (size_t)15 * SLOT_F16 + (size_t)tid * 16;  // slot 511&15
            float acc = fcb[0];
#pragma unroll 4
            for (int t2 = 0; t2 < 32; ++t2) {
                f16x8 a = *(const f16x8*)(hrow + t2 * 4096);
                f16x8 b = *(const f16x8*)(hrow + t2 * 4096 + 8);
#pragma unroll
                for (int e = 0; e < 8; ++e)
                    acc += fcW[t2 * 16 + e] * (float)a[e] + fcW[t2 * 16 + 8 + e] * (float)b[e];
            }
            out[tid] = acc;
        }
    }
}

// ---------------------------------------------------------------------------
extern "C" void kernel_launch(void* const* d_in, const int* in_sizes, int n_in,
                              void* d_out, int out_size, void* d_ws, size_t ws_size,
                              hipStream_t stream) {
    const float* x    = (const float*)d_in[0];
    const float* Wih0 = (const float*)d_in[1];
    const float* Whh0 = (const float*)d_in[2];
    const float* bih0 = (const float*)d_in[3];
    const float* bhh0 = (const float*)d_in[4];
    const float* Wih1 = (const float*)d_in[5];
    const float* Whh1 = (const float*)d_in[6];
    const float* bih1 = (const float*)d_in[7];
    const float* bhh1 = (const float*)d_in[8];
    const float* fcW  = (const float*)d_in[9];
    const float* fcb  = (const float*)d_in[10];
    char*  ws  = (char*)d_ws;
    float* out = (float*)d_out;

    if (ws_size < WS_NEED) {
        hipMemsetAsync(d_out, 0, (size_t)out_size * sizeof(float), stream);
        return;
    }

    hipFuncSetAttribute(reinterpret_cast<const void*>(lstm_persist),
                        hipFuncAttributeMaxDynamicSharedMemorySize, LDS_SIZE);

    prep_weights<<<1600, 256, 0, stream>>>(Wih0, Whh0, Wih1, Whh1, ws);
    prep_state<<<1100, 256, 0, stream>>>(bih0, bhh0, bih1, bhh1, ws);
    lstm_persist<<<256, 320, LDS_SIZE, stream>>>(ws, x, fcW, fcb, out);
}